// Round 4
// baseline (1166.020 us; speedup 1.0000x reference)
//
#include <hip/hip_runtime.h>

#define KN  50
#define NM  10          // MBON == DAN == 10
#define LPB 32          // lanes per batch element (2 batches/wave, 2 k-rows/lane)

typedef float v2f __attribute__((ext_vector_type(2)));

// mov_dpp(old=0,bound_ctrl=1) + fadd; GCNDPPCombine fuses into v_add_f32_dpp
template <int CTRL>
__device__ __forceinline__ float dpp_add(float x) {
  return x + __int_as_float(
      __builtin_amdgcn_update_dpp(0, __float_as_int(x), CTRL, 0xF, 0xF, true));
}

__device__ __forceinline__ float rowsum16(float x) {
  x = dpp_add<0x121>(x);   // row_ror:1
  x = dpp_add<0x122>(x);   // row_ror:2
  x = dpp_add<0x124>(x);   // row_ror:4
  x = dpp_add<0x128>(x);   // row_ror:8
  return x;
}

// full 32-lane sum within each 32-lane half (BitMode swizzle: xor 16, and 0x1F)
__device__ __forceinline__ float rowsum32(float x) {
  x = rowsum16(x);
  return x + __int_as_float(__builtin_amdgcn_ds_swizzle(__float_as_int(x), 0x401F));
}

__device__ __forceinline__ float bcast(int idx4, float x) {
  return __int_as_float(__builtin_amdgcn_ds_bpermute(idx4, __float_as_int(x)));
}

extern "C" __global__ void __launch_bounds__(256)
fly_kernel(const float* __restrict__ odor,    // [T,B,3]
           const float* __restrict__ ctxp,    // [T,B,1]
           const float* __restrict__ pn_w,    // [B,3,KN]
           const float* __restrict__ kn_b,    // [KN]
           const float* __restrict__ apl_w,   // [KN,1]
           const float* __restrict__ apl_b,   // [1]
           const float* __restrict__ mdw_g,   // mbon_dan_weight [DAN,MBON]
           const float* __restrict__ mbon_b,  // [MBON]
           const float* __restrict__ dmw_g,   // dan_mbon_weight [MBON,DAN]
           const float* __restrict__ ddw_g,   // dan_dan_weight [DAN,DAN]
           const float* __restrict__ dcw_g,   // dan_context_weight [1,DAN]
           const float* __restrict__ dan_b,   // [DAN]
           const float* __restrict__ decW,    // [2,MBON]
           const float* __restrict__ decb,    // [2]
           const float* __restrict__ kcw0,    // [B,KN,MBON]
           const float* __restrict__ wact0,   // [B,KN,MBON]
           float* __restrict__ out,           // [T,B,2]
           int B, int T)
{
  const int tid   = threadIdx.x;
  const int j     = tid & (LPB - 1);          // lane within batch group [0,32)
  const int jhalf = j >> 1;
  const int jodd  = j & 1;
  const int b     = blockIdx.x * (256 / LPB) + (tid >> 5);
  if (b >= B) return;

  const int base4 = (tid & 32) << 2;          // byte idx of lane 0 of this 32-lane group
  const int k2    = j + 32;                   // second owned k-row (phantom if >= KN)
  const bool has2 = k2 < KN;

  // ---- persistent plastic state: rows k=j (.x-ish -> index 0) and k=j+32 (index 1) ----
  v2f kcw[2][5], wct[2][5];
  {
    const v2f* a0 = reinterpret_cast<const v2f*>(kcw0  + ((size_t)b * KN + j) * NM);
    const v2f* w0 = reinterpret_cast<const v2f*>(wact0 + ((size_t)b * KN + j) * NM);
    #pragma unroll
    for (int h = 0; h < 5; ++h) { kcw[0][h] = a0[h]; wct[0][h] = w0[h]; }
    if (has2) {
      const v2f* a1 = reinterpret_cast<const v2f*>(kcw0  + ((size_t)b * KN + k2) * NM);
      const v2f* w1 = reinterpret_cast<const v2f*>(wact0 + ((size_t)b * KN + k2) * NM);
      #pragma unroll
      for (int h = 0; h < 5; ++h) { kcw[1][h] = a1[h]; wct[1][h] = w1[h]; }
    } else {
      v2f zz; zz.x = 0.f; zz.y = 0.f;
      #pragma unroll
      for (int h = 0; h < 5; ++h) { kcw[1][h] = zz; wct[1][h] = zz; }
    }
  }

  // ---- per-row constants packed as v2f {row0, row1}; phantom row -> zeros ----
  v2f pw0, pw1, pw2, knb, aw, kcn, lkc;
  pw0.x = pn_w[((size_t)b * 3 + 0) * KN + j];
  pw1.x = pn_w[((size_t)b * 3 + 1) * KN + j];
  pw2.x = pn_w[((size_t)b * 3 + 2) * KN + j];
  knb.x = kn_b[j];
  aw.x  = apl_w[j];
  if (has2) {
    pw0.y = pn_w[((size_t)b * 3 + 0) * KN + k2];
    pw1.y = pn_w[((size_t)b * 3 + 1) * KN + k2];
    pw2.y = pn_w[((size_t)b * 3 + 2) * KN + k2];
    knb.y = kn_b[k2];
    aw.y  = apl_w[k2];
  } else { pw0.y = 0.f; pw1.y = 0.f; pw2.y = 0.f; knb.y = 0.f; aw.y = 0.f; }
  kcn.x = 0.f; kcn.y = 0.f; lkc.x = 0.f; lkc.y = 0.f;

  // ---- per-column (m == j) small weights; lanes j>=10 hold zeros ----
  v2f mdw2[5], ddw2[5], dmw2[5];
  float cw = 0.f, db_ = 0.f, mb_ = 0.f, dw0 = 0.f, dw1 = 0.f;
  #pragma unroll
  for (int h = 0; h < 5; ++h) {
    mdw2[h].x = 0.f; mdw2[h].y = 0.f;
    ddw2[h].x = 0.f; ddw2[h].y = 0.f;
    dmw2[h].x = 0.f; dmw2[h].y = 0.f;
  }
  if (j < NM) {
    #pragma unroll
    for (int h = 0; h < 5; ++h) {
      mdw2[h].x = mdw_g[(2*h)   * NM + j];  mdw2[h].y = mdw_g[(2*h+1) * NM + j];
      ddw2[h].x = ddw_g[(2*h)   * NM + j];  ddw2[h].y = ddw_g[(2*h+1) * NM + j];
      dmw2[h].x = dmw_g[(2*h)   * NM + j];  dmw2[h].y = dmw_g[(2*h+1) * NM + j];
    }
    cw  = dcw_g[j];
    db_ = dan_b[j];
    mb_ = mbon_b[j];
    dw0 = decW[j];
    dw1 = decW[NM + j];
  }
  const float aplb = apl_b[0];
  const float db0 = decb[0], db1 = decb[1];
  const float ALPHA = (float)(0.5 / 5.5);     // DT/(DT+RC)

  // ---- recurrent small state ----
  float apl = 0.f, mbon_m = 0.f, dan_m = 0.f;
  v2f dvec2[5], ldv2[5];
  #pragma unroll
  for (int h = 0; h < 5; ++h) { dvec2[h].x = 0.f; dvec2[h].y = 0.f; ldv2[h].x = 0.f; ldv2[h].y = 0.f; }

  // pointer-increment addressing + software prefetch of next step's inputs
  const float* op = odor + (size_t)b * 3;
  const float* cp = ctxp + b;
  float* outp = out + (size_t)b * 2;
  const size_t B3 = (size_t)B * 3;

  float o0 = op[0], o1 = op[1], o2 = op[2];
  float cx = *cp;

  for (int t = 0; t < T; ++t) {
    // issue next step's loads now; consumed at the next iteration
    const float* opn = (t + 1 < T) ? op + B3 : op;
    const float* cpn = (t + 1 < T) ? cp + B  : cp;
    const float o0n = opn[0], o1n = opn[1], o2n = opn[2];
    const float cxn = *cpn;

    // --- Kenyon update (both rows packed) + kc_value/apl partial sums ---
    v2f pv  = pw0 * o0 + pw1 * o1 + pw2 * o2;
    v2f arg = pv + knb - apl;
    v2f r; r.x = fmaxf(arg.x, 0.f); r.y = fmaxf(arg.y, 0.f);
    v2f kn = 0.5f * (kcn + r);                 // dt_tau = 0.5
    kcn = kn;
    lkc = lkc + ALPHA * (kn - lkc);            // low_kc_n (new kc_n)
    v2f psum2 = kn * aw;

    v2f p2[5];
    #pragma unroll
    for (int h = 0; h < 5; ++h) p2[h] = kn.x * kcw[0][h] + kn.y * kcw[1][h];  // pre-decay kc_w

    const float psum = rowsum32(psum2.x + psum2.y);
    #pragma unroll
    for (int h = 0; h < 5; ++h) {
      p2[h].x = rowsum32(p2[h].x);
      p2[h].y = rowsum32(p2[h].y);
    }

    apl = 0.5f * apl + 0.5f * fmaxf(psum + aplb, 0.f);

    // select this lane's column value (lane m < 10 gets col m; others garbage, masked later)
    v2f rsel = p2[0];
    #pragma unroll
    for (int h = 1; h < 5; ++h) rsel = (jhalf == h) ? p2[h] : rsel;
    const float kcv = jodd ? rsel.y : rsel.x;

    // --- MBON (column j): dan_mod uses PREVIOUS dan ---
    v2f s2 = dvec2[0] * mdw2[0];
    #pragma unroll
    for (int e = 1; e < 5; ++e) s2 += dvec2[e] * mdw2[e];
    const float s = s2.x + s2.y;
    const float dmod = 1.f / (1.f + __expf(-s));
    mbon_m = 0.5f * mbon_m + 0.5f * dmod * fmaxf(kcv + mb_, 0.f);

    // --- DAN (column j): previous dan + new mbon (packed gather) ---
    v2f dp2 = dvec2[0] * ddw2[0];
    #pragma unroll
    for (int e = 1; e < 5; ++e) dp2 += dvec2[e] * ddw2[e];
    #pragma unroll
    for (int e = 0; e < 5; ++e) {
      v2f mv;
      mv.x = bcast(base4 + 8 * e,     mbon_m);
      mv.y = bcast(base4 + 8 * e + 4, mbon_m);
      dp2 += mv * dmw2[e];
    }
    const float dp = dp2.x + dp2.y + fmaf(cx, cw, db_);
    dan_m = 0.5f * dan_m + 0.5f * fmaxf(dp, 0.f);

    // broadcast new dan; update low_dan
    #pragma unroll
    for (int e = 0; e < 5; ++e) {
      dvec2[e].x = bcast(base4 + 8 * e,     dan_m);
      dvec2[e].y = bcast(base4 + 8 * e + 4, dan_m);
      ldv2[e] += ALPHA * (dvec2[e] - ldv2[e]);      // low_dan_n (new dan)
    }

    // --- decoder output (mbon garbage in lanes j>=10 masked by dw0=dw1=0;
    //     nonzero terms all in row 0 of the group -> rowsum16 suffices) ---
    const float q0 = rowsum16(mbon_m * dw0) + db0;
    const float q1 = rowsum16(mbon_m * dw1) + db1;
    if (j == 0) {
      float2 st; st.x = q0; st.y = q1;
      *reinterpret_cast<float2*>(outp) = st;
    }
    outp += (size_t)B * 2;

    // --- plasticity: kc_w decays toward OLD wact, then wact += DT*syn ---
    {
      const float kh0  =  0.5f * kcn.x, kh1  =  0.5f * kcn.y;   // DT * kc_n
      const float nlh0 = -0.5f * lkc.x, nlh1 = -0.5f * lkc.y;   // -DT * low_kc_n
      #pragma unroll
      for (int h = 0; h < 5; ++h) {
        const v2f w0 = wct[0][h], w1 = wct[1][h];
        kcw[0][h] = 0.75f * kcw[0][h] + 0.25f * w0;             // uses wact BEFORE syn
        kcw[1][h] = 0.75f * kcw[1][h] + 0.25f * w1;
        wct[0][h] = w0 + kh0 * ldv2[h] + nlh0 * dvec2[h];       // wact_n
        wct[1][h] = w1 + kh1 * ldv2[h] + nlh1 * dvec2[h];
      }
    }

    // rotate prefetched inputs
    o0 = o0n; o1 = o1n; o2 = o2n; cx = cxn;
    op = opn; cp = cpn;
  }
}

extern "C" void kernel_launch(void* const* d_in, const int* in_sizes, int n_in,
                              void* d_out, int out_size, void* d_ws, size_t ws_size,
                              hipStream_t stream) {
  const float* odor   = (const float*)d_in[0];
  const float* ctx    = (const float*)d_in[1];
  const float* pn_w   = (const float*)d_in[2];
  const float* kn_b   = (const float*)d_in[3];
  const float* apl_w  = (const float*)d_in[4];
  const float* apl_b  = (const float*)d_in[5];
  const float* mdw    = (const float*)d_in[6];
  const float* mbon_b = (const float*)d_in[7];
  const float* dmw    = (const float*)d_in[8];
  const float* ddw    = (const float*)d_in[9];
  const float* dcw    = (const float*)d_in[10];
  const float* dan_b  = (const float*)d_in[11];
  const float* decW   = (const float*)d_in[12];
  const float* decb   = (const float*)d_in[13];
  const float* kcw0   = (const float*)d_in[14];
  const float* wact0  = (const float*)d_in[15];
  float* out = (float*)d_out;

  const int B = in_sizes[14] / (KN * NM);   // kc_weight0 is [B,50,10]
  const int T = in_sizes[0] / (B * 3);      // odor is [T,B,3]

  const int batches_per_block = 256 / LPB;  // 8
  dim3 grid((B + batches_per_block - 1) / batches_per_block);
  dim3 block(256);
  hipLaunchKernelGGL(fly_kernel, grid, block, 0, stream,
                     odor, ctx, pn_w, kn_b, apl_w, apl_b,
                     mdw, mbon_b, dmw, ddw, dcw, dan_b,
                     decW, decb, kcw0, wact0, out, B, T);
}